// Round 3
// baseline (192.284 us; speedup 1.0000x reference)
//
#include <hip/hip_runtime.h>
#include <hip/hip_fp16.h>

#define N_NODES 50000
#define N_EDGES 800000
#define D_IN 128
#define HH 4
#define FF 16
#define HF 64   // HH*FF
#define CAPN 64 // per-node CSR window (entries). indeg ~ Poisson(16); P(>=64) ~ 1e-19.
#define GEMM_BLOCKS ((N_NODES + 63) / 64)                 // 782
#define BIN_EPT 4
#define BIN_GROUPS (N_EDGES / BIN_EPT)                    // 200000 int4-groups
#define BIN_BLOCKS ((BIN_GROUPS + 255) / 256)             // 782 (ceil)

struct __align__(8) Half4 { __half2 a, b; };

typedef _Float16 half2_v __attribute__((ext_vector_type(2)));
struct __align__(8) H4 { half2_v a, b; };

__device__ __forceinline__ float dot2acc(half2_v a, half2_v b, float acc) {
#if __has_builtin(__builtin_amdgcn_fdot2)
    return __builtin_amdgcn_fdot2(a, b, acc, false);
#else
    return acc + (float)a[0] * (float)b[0] + (float)a[1] * (float)b[1];
#endif
}

__device__ __forceinline__ float dot4h(H4 a, H4 v) {
    return dot2acc(a.a, v.a, dot2acc(a.b, v.b, 0.0f));
}

// ---------------- fused phase 1: edge-bin (blocks 0..781) | GEMM (blocks 782..1563) -------
// BIN first so its long-latency atomics (gcur, L2/L3-resident 200 KB) issue immediately and
// drain under the GEMM compute. Direct per-destination CSR: pos = atomicAdd(gcur[d]),
// csr[d*64+pos] = src.
// GEMM: ft = feat @ W in fp16 LDS (As[64][132]/Bst[64][136]: broadcast reads on distinct
// banks; 8 ds_read_b64 + 32 v_dot2_f32_f16 per k4; 34 KB LDS -> 4 blocks/CU). Epilogue now
// writes fth HEAD-MAJOR: fth[h][node][16] (1.6 MB per head -> per-XCD-L2-resident table for
// the per-head gather phases).
__global__ __launch_bounds__(256, 4) void fused_kernel(const float* __restrict__ feat,
                                                       const float* __restrict__ W,
                                                       __half* __restrict__ fth,
                                                       const int* __restrict__ src,
                                                       const int* __restrict__ dst,
                                                       int* __restrict__ gcur,
                                                       unsigned short* __restrict__ csr) {
    if (blockIdx.x < BIN_BLOCKS) {
        // ---- bin path: 4 edges/thread via int4 coalesced loads ----
        int gtid = blockIdx.x * 256 + threadIdx.x;
        if (gtid < BIN_GROUPS) {
            int4 s4 = ((const int4*)src)[gtid];
            int4 d4 = ((const int4*)dst)[gtid];
            int ss[4] = {s4.x, s4.y, s4.z, s4.w};
            int dd[4] = {d4.x, d4.y, d4.z, d4.w};
#pragma unroll
            for (int u = 0; u < 4; ++u) {
                int pos = atomicAdd(&gcur[dd[u]], 1);
                if (pos < CAPN) csr[(dd[u] << 6) + pos] = (unsigned short)ss[u];
            }
        }
        return;
    }

    // ---- gemm path ----
    __shared__ __half As[64][132];
    __shared__ __half Bst[64][136];

    int tid = threadIdx.x;
    int gb = blockIdx.x - BIN_BLOCKS;

    // stage W -> Bst (fp16, transposed): idx = k*16 + c4
    {
        const float4* W4 = (const float4*)W;
#pragma unroll
        for (int i = 0; i < 8; ++i) {
            int idx = tid + 256 * i;
            int k = idx >> 4;
            int c4 = idx & 15;
            float4 v = W4[idx];
            Bst[c4 * 4 + 0][k] = __float2half(v.x);
            Bst[c4 * 4 + 1][k] = __float2half(v.y);
            Bst[c4 * 4 + 2][k] = __float2half(v.z);
            Bst[c4 * 4 + 3][k] = __float2half(v.w);
        }
    }
    // stage feat tile -> As (fp16)
    {
        int row0 = gb * 64;
        const float4* F4 = (const float4*)feat;
#pragma unroll
        for (int i = 0; i < 8; ++i) {
            int idx = tid + 256 * i;
            int r = idx >> 5;
            int c4 = idx & 31;
            float4 v = make_float4(0.f, 0.f, 0.f, 0.f);
            int row = row0 + r;
            if (row < N_NODES) v = F4[(size_t)row * 32 + c4];
            Half4 h;
            h.a = __floats2half2_rn(v.x, v.y);
            h.b = __floats2half2_rn(v.z, v.w);
            *(Half4*)&As[r][c4 * 4] = h;  // byte off = r*264 + c4*8, 8B-aligned
        }
    }
    __syncthreads();

    const int tr = tid >> 4;
    const int tc = tid & 15;

    float acc[4][4] = {};
#pragma unroll 4
    for (int k4 = 0; k4 < D_IN / 4; ++k4) {
        H4 a[4], b[4];
#pragma unroll
        for (int i = 0; i < 4; ++i) a[i] = *(const H4*)&As[tr * 4 + i][k4 * 4];
#pragma unroll
        for (int c = 0; c < 4; ++c) b[c] = *(const H4*)&Bst[tc * 4 + c][k4 * 4];
#pragma unroll
        for (int i = 0; i < 4; ++i)
#pragma unroll
            for (int c = 0; c < 4; ++c)
                acc[i][c] = dot2acc(a[i].b, b[c].b, dot2acc(a[i].a, b[c].a, acc[i][c]));
    }

    // epilogue: head-major fth. Output cols tc*4..tc*4+3 all lie in head tc>>2.
    int row0 = gb * 64;
    int h = tc >> 2;
    int f0 = (tc & 3) * 4;
#pragma unroll
    for (int i = 0; i < 4; ++i) {
        int row = row0 + tr * 4 + i;
        if (row < N_NODES) {
            Half4 hh;
            hh.a = __floats2half2_rn(acc[i][0], acc[i][1]);
            hh.b = __floats2half2_rn(acc[i][2], acc[i][3]);
            *(Half4*)&fth[(size_t)h * (N_NODES * FF) + (size_t)row * FF + f0] = hh;
        }
    }
}

// ---------------- gather: per-head phases, one wave per (node, head) ----------------
// grid = (12500, 4): x-major dispatch runs ALL head-0 blocks first -> per-phase working set
// = 1.6 MB head table + ~1.6 MB csr stream + 0.2 MB gcur < 4 MB per-XCD L2. lane = g*4+fl:
// g = edge slot (0..15, 16 edges in flight), fl = feature-quad (4 halves) within the head.
// Score = 16-feature dot -> 2 shfl_xor within the 4-lane group. Softmax without
// max-subtraction (scores bounded, exp in fp32 range).
__global__ __launch_bounds__(256) void gather_kernel(const __half* __restrict__ fth,
                                                     const int* __restrict__ gcur,
                                                     const unsigned short* __restrict__ csr,
                                                     float* __restrict__ out) {
    int head = blockIdx.y;
    int node = __builtin_amdgcn_readfirstlane(blockIdx.x * 4 + (threadIdx.x >> 6));
    int lane = threadIdx.x & 63;
    int g = lane >> 2;    // edge slot
    int fl = lane & 3;    // feature-quad within head

    int cnt = gcur[node];
    if (cnt > CAPN) cnt = CAPN;
    int beg = node << 6;

    const __half* tab = fth + (size_t)head * (N_NODES * FF);
    H4 a = *(const H4*)&tab[(size_t)node * FF + fl * 4];

    float acc0 = 0.f, acc1 = 0.f, acc2 = 0.f, acc3 = 0.f, lsum = 0.f;

    for (int i = 0; i < cnt; i += 16) {
        int idx = i + g;
        bool act = idx < cnt;
        int s = csr[beg + (act ? idx : 0)];         // inactive lanes re-read edge 0 (L1 hit)
        H4 v = *(const H4*)&tab[(size_t)s * FF + fl * 4];
        float p = dot4h(a, v);
        p += __shfl_xor(p, 1, 64);
        p += __shfl_xor(p, 2, 64);
        float w = act ? __expf(p * 0.25f) : 0.0f;
        acc0 = fmaf(w, (float)v.a[0], acc0);
        acc1 = fmaf(w, (float)v.a[1], acc1);
        acc2 = fmaf(w, (float)v.b[0], acc2);
        acc3 = fmaf(w, (float)v.b[1], acc3);
        lsum += w;
    }

    // reduce across the 16 edge slots (lanes ^4, ^8, ^16, ^32 hold same feature-quad)
#pragma unroll
    for (int off = 4; off <= 32; off <<= 1) {
        acc0 += __shfl_xor(acc0, off, 64);
        acc1 += __shfl_xor(acc1, off, 64);
        acc2 += __shfl_xor(acc2, off, 64);
        acc3 += __shfl_xor(acc3, off, 64);
        lsum += __shfl_xor(lsum, off, 64);
    }

    if (g == 0) {
        float inv = (lsum > 0.0f) ? 1.0f / lsum : 0.0f;
        *(float4*)&out[(size_t)node * HF + head * FF + fl * 4] =
            make_float4(acc0 * inv, acc1 * inv, acc2 * inv, acc3 * inv);
    }
}

extern "C" void kernel_launch(void* const* d_in, const int* in_sizes, int n_in,
                              void* d_out, int out_size, void* d_ws, size_t ws_size,
                              hipStream_t stream) {
    const float* feat = (const float*)d_in[0];
    const float* W = (const float*)d_in[1];
    const int* src = (const int*)d_in[2];
    const int* dst = (const int*)d_in[3];
    float* out = (float*)d_out;

    // workspace layout (all 16B-aligned): 6.4 MB + 6.4 MB + 0.2 MB = 13.0 MB
    __half* fth = (__half*)d_ws;                                          // 4 x N x 16 halves
    unsigned short* csr = (unsigned short*)(fth + (size_t)HH * N_NODES * FF); // N*64 ushorts
    int* gcur = (int*)(csr + (size_t)N_NODES * CAPN);                     // N ints

    hipMemsetAsync(gcur, 0, N_NODES * sizeof(int), stream);
    fused_kernel<<<BIN_BLOCKS + GEMM_BLOCKS, 256, 0, stream>>>(feat, W, fth, src, dst, gcur, csr);
    gather_kernel<<<dim3(N_NODES / 4, HH), 256, 0, stream>>>(fth, gcur, csr, out);
}

// Round 4
// 154.785 us; speedup vs baseline: 1.2423x; 1.2423x over previous
//
#include <hip/hip_runtime.h>
#include <hip/hip_fp16.h>

#define N_NODES 50000
#define N_EDGES 800000
#define D_IN 128
#define HH 4
#define FF 16
#define HF 64   // HH*FF
#define CAPN 64 // per-node CSR window (entries). indeg ~ Poisson(16); P(>=64) ~ 1e-19.
#define GEMM_BLOCKS ((N_NODES + 63) / 64)                 // 782
#define BIN_EPT 4
#define BIN_GROUPS (N_EDGES / BIN_EPT)                    // 200000 int4-groups
#define BIN_BLOCKS ((BIN_GROUPS + 255) / 256)             // 782 (ceil)

struct __align__(8) Half4 { __half2 a, b; };

typedef _Float16 half2_v __attribute__((ext_vector_type(2)));
typedef _Float16 half8_v __attribute__((ext_vector_type(8)));  // 16B = one dwordx4 load
struct __align__(8) H4 { half2_v a, b; };

__device__ __forceinline__ float dot2acc(half2_v a, half2_v b, float acc) {
#if __has_builtin(__builtin_amdgcn_fdot2)
    return __builtin_amdgcn_fdot2(a, b, acc, false);
#else
    return acc + (float)a[0] * (float)b[0] + (float)a[1] * (float)b[1];
#endif
}

// dot of two half8 vectors accumulated into fp32 (4 x v_dot2_f32_f16).
__device__ __forceinline__ float dot8acc(half8_v a, half8_v b, float acc) {
#pragma unroll
    for (int j = 0; j < 4; ++j) {
        half2_v ax = {a[2 * j], a[2 * j + 1]};
        half2_v bx = {b[2 * j], b[2 * j + 1]};
        acc = dot2acc(ax, bx, acc);
    }
    return acc;
}

// ---------------- fused phase 1: GEMM (blocks 0..781) | edge-bin (blocks 782..1563) -------
// ROUND-2 configuration restored (GEMM first, node-major fth): bin-first (round 3) filled
// the machine with pure-atomic blocks and lost the GEMM overlap -> fused 47->82us.
// GEMM: ft[N,64] = feat[N,128] @ W[128,64], all-fp16 LDS (As[64][132]/Bst[64][136] strides
// keep broadcast reads on distinct banks; 8 ds_read_b64 + 32 v_dot2_f32_f16 per k4; 34 KB
// LDS -> 4 blocks/CU).
// BIN: direct per-destination CSR scatter: pos = atomicAdd(gcur[d]), csr[d*64+pos] = src.
__global__ __launch_bounds__(256, 4) void fused_kernel(const float* __restrict__ feat,
                                                       const float* __restrict__ W,
                                                       __half* __restrict__ fth,
                                                       const int* __restrict__ src,
                                                       const int* __restrict__ dst,
                                                       int* __restrict__ gcur,
                                                       unsigned short* __restrict__ csr) {
    if (blockIdx.x >= GEMM_BLOCKS) {
        // ---- bin path: 4 edges/thread via int4 coalesced loads ----
        int gtid = (blockIdx.x - GEMM_BLOCKS) * 256 + threadIdx.x;
        if (gtid < BIN_GROUPS) {
            int4 s4 = ((const int4*)src)[gtid];
            int4 d4 = ((const int4*)dst)[gtid];
            int ss[4] = {s4.x, s4.y, s4.z, s4.w};
            int dd[4] = {d4.x, d4.y, d4.z, d4.w};
#pragma unroll
            for (int u = 0; u < 4; ++u) {
                int pos = atomicAdd(&gcur[dd[u]], 1);
                if (pos < CAPN) csr[(dd[u] << 6) + pos] = (unsigned short)ss[u];
            }
        }
        return;
    }

    // ---- gemm path ----
    __shared__ __half As[64][132];
    __shared__ __half Bst[64][136];

    int tid = threadIdx.x;
    int gb = blockIdx.x;

    // stage W -> Bst (fp16, transposed): idx = k*16 + c4
    {
        const float4* W4 = (const float4*)W;
#pragma unroll
        for (int i = 0; i < 8; ++i) {
            int idx = tid + 256 * i;
            int k = idx >> 4;
            int c4 = idx & 15;
            float4 v = W4[idx];
            Bst[c4 * 4 + 0][k] = __float2half(v.x);
            Bst[c4 * 4 + 1][k] = __float2half(v.y);
            Bst[c4 * 4 + 2][k] = __float2half(v.z);
            Bst[c4 * 4 + 3][k] = __float2half(v.w);
        }
    }
    // stage feat tile -> As (fp16)
    {
        int row0 = gb * 64;
        const float4* F4 = (const float4*)feat;
#pragma unroll
        for (int i = 0; i < 8; ++i) {
            int idx = tid + 256 * i;
            int r = idx >> 5;
            int c4 = idx & 31;
            float4 v = make_float4(0.f, 0.f, 0.f, 0.f);
            int row = row0 + r;
            if (row < N_NODES) v = F4[(size_t)row * 32 + c4];
            Half4 h;
            h.a = __floats2half2_rn(v.x, v.y);
            h.b = __floats2half2_rn(v.z, v.w);
            *(Half4*)&As[r][c4 * 4] = h;  // byte off = r*264 + c4*8, 8B-aligned
        }
    }
    __syncthreads();

    const int tr = tid >> 4;
    const int tc = tid & 15;

    float acc[4][4] = {};
#pragma unroll 4
    for (int k4 = 0; k4 < D_IN / 4; ++k4) {
        H4 a[4], b[4];
#pragma unroll
        for (int i = 0; i < 4; ++i) a[i] = *(const H4*)&As[tr * 4 + i][k4 * 4];
#pragma unroll
        for (int c = 0; c < 4; ++c) b[c] = *(const H4*)&Bst[tc * 4 + c][k4 * 4];
#pragma unroll
        for (int i = 0; i < 4; ++i)
#pragma unroll
            for (int c = 0; c < 4; ++c)
                acc[i][c] = dot2acc(a[i].b, b[c].b, dot2acc(a[i].a, b[c].a, acc[i][c]));
    }

    int row0 = gb * 64;
#pragma unroll
    for (int i = 0; i < 4; ++i) {
        int row = row0 + tr * 4 + i;
        if (row < N_NODES) {
            Half4 h;
            h.a = __floats2half2_rn(acc[i][0], acc[i][1]);
            h.b = __floats2half2_rn(acc[i][2], acc[i][3]);
            *(Half4*)&fth[(size_t)row * HF + tc * 4] = h;
        }
    }
}

// ---------------- gather: one wave per node, 16 edges in flight, 4 lanes/edge -------------
// lane = e*4 + h: e = edge slot (0..15), h = HEAD. Lane h owns the 16 contiguous features
// of head h -> the per-head score is a lane-local 16-feature dot: ZERO score shuffles
// (round-2 spent 8 shfl_xor/iter on it). Avg indegree 16 -> the typical node finishes in
// ONE iteration = one exposed load round-trip (round-2's 4-edges-in-flight exposed 4).
// Per edge: 4 lanes x two dwordx4 = the full 128B row, coalesced. Per-head softmax without
// max-subtraction (scores bounded, exp in fp32 range). Only the final cross-edge-slot
// reduce shuffles (offsets 4/8/16/32, 17 values).
__global__ __launch_bounds__(256) void gather_kernel(const __half* __restrict__ fth,
                                                     const int* __restrict__ gcur,
                                                     const unsigned short* __restrict__ csr,
                                                     float* __restrict__ out) {
    int node = __builtin_amdgcn_readfirstlane(blockIdx.x * 4 + (threadIdx.x >> 6));
    int lane = threadIdx.x & 63;
    int e = lane >> 2;    // edge slot
    int h = lane & 3;     // head index = 16-feature block

    int cnt = gcur[node];
    if (cnt > CAPN) cnt = CAPN;
    int beg = node << 6;

    const __half* myrow = &fth[(size_t)node * HF + h * FF];
    half8_v a0 = *(const half8_v*)myrow;
    half8_v a1 = *(const half8_v*)(myrow + 8);

    float acc[FF] = {};
    float lsum = 0.f;

    for (int i = 0; i < cnt; i += 16) {
        int idx = i + e;
        bool act = idx < cnt;
        int s = act ? (int)csr[beg + idx] : 0;  // inactive -> row 0 (hot line, w=0 below)
        const __half* vr = &fth[(size_t)s * HF + h * FF];
        half8_v v0 = *(const half8_v*)vr;
        half8_v v1 = *(const half8_v*)(vr + 8);
        float p = dot8acc(a1, v1, dot8acc(a0, v0, 0.0f));  // e[edge][h], lane-local
        float w = act ? __expf(p * 0.25f) : 0.0f;
        lsum += w;
#pragma unroll
        for (int j = 0; j < 8; ++j) acc[j] = fmaf(w, (float)v0[j], acc[j]);
#pragma unroll
        for (int j = 0; j < 8; ++j) acc[8 + j] = fmaf(w, (float)v1[j], acc[8 + j]);
    }

    // reduce across the 16 edge slots; lanes with equal (lane&3) share a head.
#pragma unroll
    for (int off = 4; off <= 32; off <<= 1) {
#pragma unroll
        for (int j = 0; j < FF; ++j) acc[j] += __shfl_xor(acc[j], off, 64);
        lsum += __shfl_xor(lsum, off, 64);
    }

    if (e == 0) {
        float inv = (lsum > 0.0f) ? 1.0f / lsum : 0.0f;
        float4* o = (float4*)&out[(size_t)node * HF + h * FF];
        o[0] = make_float4(acc[0] * inv, acc[1] * inv, acc[2] * inv, acc[3] * inv);
        o[1] = make_float4(acc[4] * inv, acc[5] * inv, acc[6] * inv, acc[7] * inv);
        o[2] = make_float4(acc[8] * inv, acc[9] * inv, acc[10] * inv, acc[11] * inv);
        o[3] = make_float4(acc[12] * inv, acc[13] * inv, acc[14] * inv, acc[15] * inv);
    }
}

extern "C" void kernel_launch(void* const* d_in, const int* in_sizes, int n_in,
                              void* d_out, int out_size, void* d_ws, size_t ws_size,
                              hipStream_t stream) {
    const float* feat = (const float*)d_in[0];
    const float* W = (const float*)d_in[1];
    const int* src = (const int*)d_in[2];
    const int* dst = (const int*)d_in[3];
    float* out = (float*)d_out;

    // workspace layout (all 16B-aligned): 6.4 MB + 6.4 MB + 0.2 MB = 13.0 MB
    __half* fth = (__half*)d_ws;                                          // N*64 halves
    unsigned short* csr = (unsigned short*)(fth + (size_t)N_NODES * HF);  // N*64 ushorts
    int* gcur = (int*)(csr + (size_t)N_NODES * CAPN);                     // N ints

    hipMemsetAsync(gcur, 0, N_NODES * sizeof(int), stream);
    fused_kernel<<<GEMM_BLOCKS + BIN_BLOCKS, 256, 0, stream>>>(feat, W, fth, src, dst, gcur, csr);
    gather_kernel<<<N_NODES / 4, 256, 0, stream>>>(fth, gcur, csr, out);
}

// Round 6
// 142.850 us; speedup vs baseline: 1.3461x; 1.0836x over previous
//
#include <hip/hip_runtime.h>
#include <hip/hip_fp16.h>

#define N_NODES 50000
#define N_EDGES 800000
#define D_IN 128
#define HH 4
#define FF 16
#define HF 64   // HH*FF
#define CAPN 64 // per-node CSR window (entries). indeg ~ Poisson(16); P(>=64) ~ 1e-19.
#define GEMM_BLOCKS ((N_NODES + 63) / 64)                 // 782
#define BIN_EPT 4
#define BIN_GROUPS (N_EDGES / BIN_EPT)                    // 200000 int4-groups
#define BIN_BLOCKS ((BIN_GROUPS + 255) / 256)             // 782 (ceil)

struct __align__(8) Half4 { __half2 a, b; };

typedef _Float16 half2_v __attribute__((ext_vector_type(2)));
struct __align__(8) H4 { half2_v a, b; };

__device__ __forceinline__ float dot2acc(half2_v a, half2_v b, float acc) {
#if __has_builtin(__builtin_amdgcn_fdot2)
    return __builtin_amdgcn_fdot2(a, b, acc, false);
#else
    return acc + (float)a[0] * (float)b[0] + (float)a[1] * (float)b[1];
#endif
}

__device__ __forceinline__ float dot4h(H4 a, H4 v) {
    return dot2acc(a.a, v.a, dot2acc(a.b, v.b, 0.0f));
}

// ---------------- fused phase 1: GEMM (blocks 0..781) | edge-bin (blocks 782..1563) -------
// EXACT round-2 structure (measured 138.0 total / fused 47.5) with ONE change: the two
// producer->consumer surfaces (fth, csr) are written with NONTEMPORAL stores. Theory:
// regular stores leave these lines modified-exclusive in the writer XCD's L2; the gather
// (and the bin scatter itself) then pays a cross-XCD dirty-line coherence fetch per first
// touch. NT stores push them memory-side (L3) clean, so consumers read shared lines.
// (Round-5 attempt failed to COMPILE: the builtin rejects HIP vector-type pointers; the
// 8B fth store now goes through unsigned long long.)
__global__ __launch_bounds__(256, 4) void fused_kernel(const float* __restrict__ feat,
                                                       const float* __restrict__ W,
                                                       __half* __restrict__ fth,
                                                       const int* __restrict__ src,
                                                       const int* __restrict__ dst,
                                                       int* __restrict__ gcur,
                                                       unsigned short* __restrict__ csr) {
    if (blockIdx.x >= GEMM_BLOCKS) {
        // ---- bin path: 4 edges/thread via int4 coalesced loads ----
        int gtid = (blockIdx.x - GEMM_BLOCKS) * 256 + threadIdx.x;
        if (gtid < BIN_GROUPS) {
            int4 s4 = ((const int4*)src)[gtid];
            int4 d4 = ((const int4*)dst)[gtid];
            int ss[4] = {s4.x, s4.y, s4.z, s4.w};
            int dd[4] = {d4.x, d4.y, d4.z, d4.w};
#pragma unroll
            for (int u = 0; u < 4; ++u) {
                int pos = atomicAdd(&gcur[dd[u]], 1);
                if (pos < CAPN)
                    __builtin_nontemporal_store((unsigned short)ss[u], &csr[(dd[u] << 6) + pos]);
            }
        }
        return;
    }

    // ---- gemm path ----
    __shared__ __half As[64][132];
    __shared__ __half Bst[64][136];

    int tid = threadIdx.x;
    int gb = blockIdx.x;

    // stage W -> Bst (fp16, transposed): idx = k*16 + c4
    {
        const float4* W4 = (const float4*)W;
#pragma unroll
        for (int i = 0; i < 8; ++i) {
            int idx = tid + 256 * i;
            int k = idx >> 4;
            int c4 = idx & 15;
            float4 v = W4[idx];
            Bst[c4 * 4 + 0][k] = __float2half(v.x);
            Bst[c4 * 4 + 1][k] = __float2half(v.y);
            Bst[c4 * 4 + 2][k] = __float2half(v.z);
            Bst[c4 * 4 + 3][k] = __float2half(v.w);
        }
    }
    // stage feat tile -> As (fp16)
    {
        int row0 = gb * 64;
        const float4* F4 = (const float4*)feat;
#pragma unroll
        for (int i = 0; i < 8; ++i) {
            int idx = tid + 256 * i;
            int r = idx >> 5;
            int c4 = idx & 31;
            float4 v = make_float4(0.f, 0.f, 0.f, 0.f);
            int row = row0 + r;
            if (row < N_NODES) v = F4[(size_t)row * 32 + c4];
            Half4 h;
            h.a = __floats2half2_rn(v.x, v.y);
            h.b = __floats2half2_rn(v.z, v.w);
            *(Half4*)&As[r][c4 * 4] = h;  // byte off = r*264 + c4*8, 8B-aligned
        }
    }
    __syncthreads();

    const int tr = tid >> 4;
    const int tc = tid & 15;

    float acc[4][4] = {};
#pragma unroll 4
    for (int k4 = 0; k4 < D_IN / 4; ++k4) {
        H4 a[4], b[4];
#pragma unroll
        for (int i = 0; i < 4; ++i) a[i] = *(const H4*)&As[tr * 4 + i][k4 * 4];
#pragma unroll
        for (int c = 0; c < 4; ++c) b[c] = *(const H4*)&Bst[tc * 4 + c][k4 * 4];
#pragma unroll
        for (int i = 0; i < 4; ++i)
#pragma unroll
            for (int c = 0; c < 4; ++c)
                acc[i][c] = dot2acc(a[i].b, b[c].b, dot2acc(a[i].a, b[c].a, acc[i][c]));
    }

    int row0 = gb * 64;
#pragma unroll
    for (int i = 0; i < 4; ++i) {
        int row = row0 + tr * 4 + i;
        if (row < N_NODES) {
            Half4 h;
            h.a = __floats2half2_rn(acc[i][0], acc[i][1]);
            h.b = __floats2half2_rn(acc[i][2], acc[i][3]);
            // nontemporal 8B store via integer type (builtin rejects HIP vector types)
            unsigned long long bits;
            __builtin_memcpy(&bits, &h, 8);
            __builtin_nontemporal_store(bits,
                (unsigned long long*)&fth[(size_t)row * HF + tc * 4]);
        }
    }
}

// ---------------- gather: EXACT round-2 shape (one wave/node, 16 edges in flight, ---------
// 4 edge-quad slots x 16 feature-lanes; ushort4 csr fetch; 2 shfl_xor per score; softmax
// without max-subtraction; 10-shuffle epilogue). Unchanged for single-variable A/B.
__global__ __launch_bounds__(256) void gather_kernel(const __half* __restrict__ fth,
                                                     const int* __restrict__ gcur,
                                                     const unsigned short* __restrict__ csr,
                                                     float* __restrict__ out) {
    int node = __builtin_amdgcn_readfirstlane(blockIdx.x * 4 + (threadIdx.x >> 6));
    int lane = threadIdx.x & 63;
    int g = lane >> 4;     // edge-quad slot within wave
    int hl = lane & 15;    // feature-quad index

    int cnt = gcur[node];
    if (cnt > CAPN) cnt = CAPN;
    int beg = node << 6;
    int end = beg + cnt;

    H4 a = *(const H4*)&fth[(size_t)node * HF + 4 * hl];

    float acc0 = 0.f, acc1 = 0.f, acc2 = 0.f, acc3 = 0.f, lsum = 0.f;

    for (int i = beg; i < end; i += 16) {
        int idx0 = i + 4 * g;
        ushort4 sv = *(const ushort4*)&csr[idx0];  // never escapes the 64-entry window
        int s[4];
        bool act[4];
        H4 v[4];
        float p[4];
        s[0] = sv.x; s[1] = sv.y; s[2] = sv.z; s[3] = sv.w;
#pragma unroll
        for (int u = 0; u < 4; ++u) {
            act[u] = (idx0 + u) < end;
            if (!act[u]) s[u] = 0;  // garbage beyond cnt -> clamp to a valid row
        }
#pragma unroll
        for (int u = 0; u < 4; ++u) v[u] = *(const H4*)&fth[(size_t)s[u] * HF + 4 * hl];
#pragma unroll
        for (int u = 0; u < 4; ++u) p[u] = dot4h(a, v[u]);
#pragma unroll
        for (int u = 0; u < 4; ++u) p[u] += __shfl_xor(p[u], 1, 64);
#pragma unroll
        for (int u = 0; u < 4; ++u) p[u] += __shfl_xor(p[u], 2, 64);
#pragma unroll
        for (int u = 0; u < 4; ++u) {
            float w = act[u] ? __expf(p[u] * 0.25f) : 0.0f;
            acc0 = fmaf(w, (float)v[u].a[0], acc0);
            acc1 = fmaf(w, (float)v[u].a[1], acc1);
            acc2 = fmaf(w, (float)v[u].b[0], acc2);
            acc3 = fmaf(w, (float)v[u].b[1], acc3);
            lsum += w;
        }
    }

    // reduce across the 4 edge-quad slots (lanes ^16, ^32 hold same features)
    acc0 += __shfl_xor(acc0, 16, 64);  acc0 += __shfl_xor(acc0, 32, 64);
    acc1 += __shfl_xor(acc1, 16, 64);  acc1 += __shfl_xor(acc1, 32, 64);
    acc2 += __shfl_xor(acc2, 16, 64);  acc2 += __shfl_xor(acc2, 32, 64);
    acc3 += __shfl_xor(acc3, 16, 64);  acc3 += __shfl_xor(acc3, 32, 64);
    lsum += __shfl_xor(lsum, 16, 64);  lsum += __shfl_xor(lsum, 32, 64);

    if (lane < 16) {
        float inv = (lsum > 0.0f) ? 1.0f / lsum : 0.0f;
        *(float4*)&out[(size_t)node * HF + 4 * hl] =
            make_float4(acc0 * inv, acc1 * inv, acc2 * inv, acc3 * inv);
    }
}

extern "C" void kernel_launch(void* const* d_in, const int* in_sizes, int n_in,
                              void* d_out, int out_size, void* d_ws, size_t ws_size,
                              hipStream_t stream) {
    const float* feat = (const float*)d_in[0];
    const float* W = (const float*)d_in[1];
    const int* src = (const int*)d_in[2];
    const int* dst = (const int*)d_in[3];
    float* out = (float*)d_out;

    // workspace layout (all 16B-aligned): 6.4 MB + 6.4 MB + 0.2 MB = 13.0 MB
    __half* fth = (__half*)d_ws;                                          // N*64 halves
    unsigned short* csr = (unsigned short*)(fth + (size_t)N_NODES * HF);  // N*64 ushorts
    int* gcur = (int*)(csr + (size_t)N_NODES * CAPN);                     // N ints

    (void)hipMemsetAsync(gcur, 0, N_NODES * sizeof(int), stream);
    fused_kernel<<<GEMM_BLOCKS + BIN_BLOCKS, 256, 0, stream>>>(feat, W, fth, src, dst, gcur, csr);
    gather_kernel<<<N_NODES / 4, 256, 0, stream>>>(fth, gcur, csr, out);
}